// Round 10
// baseline (987.723 us; speedup 1.0000x reference)
//
#include <hip/hip_runtime.h>
#include <hip/hip_bf16.h>
#include <math.h>

// Problem constants
constexpr int Bb  = 4;
constexpr int Tt  = 2048;
constexpr int DM  = 1024;
constexpr int NH  = 16;
constexpr int HD  = 64;
constexpr int MBT = Bb * Tt;                       // 8192
constexpr float LOG_THETA = 9.210340371976184f;    // ln(10000)

using bf16x8 = __attribute__((ext_vector_type(8))) short;   // 8 bf16 (4 VGPRs)
using f32x4  = __attribute__((ext_vector_type(4))) float;   // MFMA accumulator

__device__ inline short f2bf(float x) {
    __hip_bfloat16 h = __float2bfloat16(x);
    return *reinterpret_cast<short*>(&h);
}
__device__ inline float bf2f(short u) {
    __hip_bfloat16 h;
    *reinterpret_cast<short*>(&h) = u;
    return __bfloat162float(h);
}
__device__ inline unsigned int packbf2(float x) {
    short h  = f2bf(x);
    short lo = f2bf(x - bf2f(h));
    return (unsigned int)(unsigned short)h | ((unsigned int)(unsigned short)lo << 16);
}
// 8 fp32 -> bf16 hi/lo vectors (all indices static after unroll)
__device__ inline void split8(float4 a, float4 b, bf16x8& H, bf16x8& L) {
    float x[8] = {a.x, a.y, a.z, a.w, b.x, b.y, b.z, b.w};
    #pragma unroll
    for (int e = 0; e < 8; ++e) {
        short h = f2bf(x[e]);
        H[e] = h;
        L[e] = f2bf(x[e] - bf2f(h));
    }
}

// ---------------------------------------------------------------------------
// RoPE cos/sin table: tab[t*64 + 2p] = cos(t*theta^(-2p/64)), +1 = sin.
// ---------------------------------------------------------------------------
__global__ __launch_bounds__(256) void rope_table(float* __restrict__ tab)
{
    int i = blockIdx.x * 256 + threadIdx.x;   // 0..65535
    int t = i >> 5, p = i & 31;
    float freq = expf(-(float)(2 * p) * (LOG_THETA / 64.0f));
    float ang  = (float)t * freq;
    tab[t * 64 + 2 * p]     = cosf(ang);
    tab[t * 64 + 2 * p + 1] = sinf(ang);
}

// ---------------------------------------------------------------------------
// fp32 -> bf16 hi/lo split arrays. 4 elems/thread.
// ---------------------------------------------------------------------------
__global__ __launch_bounds__(256) void cast_split(
    const float* __restrict__ src, short* __restrict__ hi,
    short* __restrict__ lo, int n4)
{
    int i = blockIdx.x * 256 + threadIdx.x;
    if (i >= n4) return;
    float4 v = reinterpret_cast<const float4*>(src)[i];
    short h0 = f2bf(v.x), h1 = f2bf(v.y), h2 = f2bf(v.z), h3 = f2bf(v.w);
    short l0 = f2bf(v.x - bf2f(h0));
    short l1 = f2bf(v.y - bf2f(h1));
    short l2 = f2bf(v.z - bf2f(h2));
    short l3 = f2bf(v.w - bf2f(h3));
    reinterpret_cast<short4*>(hi)[i] = make_short4(h0, h1, h2, h3);
    reinterpret_cast<short4*>(lo)[i] = make_short4(l0, l1, l2, l3);
}

// ---------------------------------------------------------------------------
// Kernel 1: QKV GEMM via bf16x3 MFMA (~fp32 precision).
// C[8192,3072] = X * Wqkv^T. 128x128 tile, BK=32, 4 waves (2x2), 4x4 frags.
// XCD-aware swizzle (T1): 1536 blocks % 8 == 0, bijective chunk remap so
// consecutive work ids (sharing an A-panel) land on the same XCD's L2.
// Epilogue: RoPE + scatter.
//   Q  -> fp32 [bh][t][64]
//   K  -> bf16 hi/lo arrays Khi/Klo [bh][t][64]   (pre-split for attn)
//   V  -> bf16 hi/lo arrays Vthi/Vtlo [bh][64 d][t]  (TRANSPOSED for attn)
// ---------------------------------------------------------------------------
__global__ __launch_bounds__(256) void gemm_qkv_mfma(
    const short* __restrict__ Xhi, const short* __restrict__ Xlo,
    const short* __restrict__ Whi, const short* __restrict__ Wlo,
    const float* __restrict__ tab,
    float* __restrict__ Qo,
    unsigned short* __restrict__ Khi_g, unsigned short* __restrict__ Klo_g,
    unsigned short* __restrict__ Vthi_g, unsigned short* __restrict__ Vtlo_g)
{
    __shared__ __align__(16) short Ah[4096], Al[4096], Bh[4096], Bl[4096];
    const int tid = threadIdx.x;
    // XCD swizzle: dispatch id d -> work id wid; chunk = 1536/8 = 192.
    const int d_  = (int)blockIdx.y * (int)gridDim.x + (int)blockIdx.x;
    const int wid = (d_ & 7) * 192 + (d_ >> 3);
    const int bm  = (wid / 24) * 128;
    const int bn  = (wid % 24) * 128;
    const int w   = tid >> 6, l = tid & 63;
    const int wr  = w >> 1,  wc = w & 1;

    const int r0 = tid >> 2;
    const int c0 = (tid & 3) * 8;
    const size_t ga0 = (size_t)(bm + r0) * 1024 + c0;
    const size_t ga1 = (size_t)(bm + r0 + 64) * 1024 + c0;
    const size_t gb0 = (size_t)(bn + r0) * 1024 + c0;
    const size_t gb1 = (size_t)(bn + r0 + 64) * 1024 + c0;

    f32x4 acc[4][4];
    #pragma unroll
    for (int m = 0; m < 4; ++m)
        #pragma unroll
        for (int n = 0; n < 4; ++n) acc[m][n] = (f32x4){0.f, 0.f, 0.f, 0.f};

    float4 pah0 = *(const float4*)(Xhi + ga0);
    float4 pah1 = *(const float4*)(Xhi + ga1);
    float4 pal0 = *(const float4*)(Xlo + ga0);
    float4 pal1 = *(const float4*)(Xlo + ga1);
    float4 pbh0 = *(const float4*)(Whi + gb0);
    float4 pbh1 = *(const float4*)(Whi + gb1);
    float4 pbl0 = *(const float4*)(Wlo + gb0);
    float4 pbl1 = *(const float4*)(Wlo + gb1);

    for (int k0 = 0; k0 < 1024; k0 += 32) {
        __syncthreads();
        *(float4*)&Ah[tid * 8] = pah0;  *(float4*)&Ah[(tid + 256) * 8] = pah1;
        *(float4*)&Al[tid * 8] = pal0;  *(float4*)&Al[(tid + 256) * 8] = pal1;
        *(float4*)&Bh[tid * 8] = pbh0;  *(float4*)&Bh[(tid + 256) * 8] = pbh1;
        *(float4*)&Bl[tid * 8] = pbl0;  *(float4*)&Bl[(tid + 256) * 8] = pbl1;
        int kn = (k0 + 32) & 1023;
        pah0 = *(const float4*)(Xhi + ga0 + kn);
        pah1 = *(const float4*)(Xhi + ga1 + kn);
        pal0 = *(const float4*)(Xlo + ga0 + kn);
        pal1 = *(const float4*)(Xlo + ga1 + kn);
        pbh0 = *(const float4*)(Whi + gb0 + kn);
        pbh1 = *(const float4*)(Whi + gb1 + kn);
        pbl0 = *(const float4*)(Wlo + gb0 + kn);
        pbl1 = *(const float4*)(Wlo + gb1 + kn);
        __syncthreads();

        const int fr = l & 15;
        const int fg = (l >> 4) * 8;
        bf16x8 ah[4], alo[4], bhv[4], blo[4];
        #pragma unroll
        for (int m = 0; m < 4; ++m) {
            int ro = (wr * 64 + m * 16 + fr) * 32 + fg;
            ah[m]  = *(const bf16x8*)&Ah[ro];
            alo[m] = *(const bf16x8*)&Al[ro];
        }
        #pragma unroll
        for (int n = 0; n < 4; ++n) {
            int ro = (wc * 64 + n * 16 + fr) * 32 + fg;
            bhv[n] = *(const bf16x8*)&Bh[ro];
            blo[n] = *(const bf16x8*)&Bl[ro];
        }
        #pragma unroll
        for (int m = 0; m < 4; ++m)
            #pragma unroll
            for (int n = 0; n < 4; ++n) {
                acc[m][n] = __builtin_amdgcn_mfma_f32_16x16x32_bf16(ah[m],  bhv[n], acc[m][n], 0, 0, 0);
                acc[m][n] = __builtin_amdgcn_mfma_f32_16x16x32_bf16(ah[m],  blo[n], acc[m][n], 0, 0, 0);
                acc[m][n] = __builtin_amdgcn_mfma_f32_16x16x32_bf16(alo[m], bhv[n], acc[m][n], 0, 0, 0);
            }
    }

    // Epilogue: C/D layout col = lane&15, row = (lane>>4)*4 + reg (m89).
    const int fr = l & 15, fq = l >> 4;
    #pragma unroll
    for (int m = 0; m < 4; ++m) {
        #pragma unroll
        for (int n = 0; n < 4; ++n) {
            int col  = bn + wc * 64 + n * 16 + fr;
            int sect = col >> 10;          // 0=q 1=k 2=v (wave-uniform)
            int cc   = col & 1023;
            int hh   = cc >> 6, d = cc & 63;
            int de   = d & 62;
            #pragma unroll
            for (int i = 0; i < 4; ++i) {
                int r  = bm + wr * 64 + m * 16 + fq * 4 + i;
                int b_ = r >> 11, t_ = r & 2047;
                float v  = acc[m][n][i];
                float vn = __shfl_xor(v, 1);
                if (sect == 2) {
                    // V transposed + pre-split: Vt[bh][d][t]
                    size_t off = ((size_t)(b_ * NH + hh) * HD + d) * Tt + t_;
                    short h = f2bf(v);
                    Vthi_g[off] = (unsigned short)h;
                    Vtlo_g[off] = (unsigned short)f2bf(v - bf2f(h));
                } else {
                    float2 cssn = *(const float2*)(tab + t_ * 64 + de);
                    float outv = (d & 1) ? (vn * cssn.y + v * cssn.x)
                                         : (v * cssn.x - vn * cssn.y);
                    size_t off = ((size_t)(b_ * NH + hh) * Tt + t_) * HD + d;
                    if (sect == 0) {
                        Qo[off] = outv;
                    } else {
                        short h = f2bf(outv);
                        Khi_g[off] = (unsigned short)h;
                        Klo_g[off] = (unsigned short)f2bf(outv - bf2f(h));
                    }
                }
            }
        }
    }
}

// ---------------------------------------------------------------------------
// Kernel 2: causal flash attention, MFMA bf16-hi/lo x3 (~fp32 precision).
// Grid (32, B*H); qi = 31 - blockIdx.x (longest blocks dispatch FIRST).
// Block 256 = 4 waves; wave w owns q-rows [qi*64+w*16, +16).
// T14 pipeline: next tile's K/Vt prefetched into REGISTERS right after the
// "LDS ready" barrier (loads hide under MFMA+softmax), written to swizzled
// LDS at the top of the next iteration. 2 barriers/tile, loads off the
// critical path.
// ---------------------------------------------------------------------------
__global__ __launch_bounds__(256) void attn_fwd_mfma(
    const float* Q,
    const unsigned short* __restrict__ Khi_g, const unsigned short* __restrict__ Klo_g,
    const unsigned short* __restrict__ Vthi_g, const unsigned short* __restrict__ Vtlo_g,
    unsigned int* Opk)
{
    __shared__ __align__(16) short Khi[4096], Klo[4096], Vthi[4096], Vtlo[4096];
    __shared__ __align__(16) unsigned int Ppk[4][16][68];   // pad 64->68

    const int tid = threadIdx.x;
    const int w   = tid >> 6;
    const int l   = tid & 63;
    const int fr  = l & 15;
    const int hi8 = l >> 4;
    const int bh  = blockIdx.y;
    const int qi  = (int)gridDim.x - 1 - (int)blockIdx.x;   // longest-first
    const int qbase = qi * 64 + w * 16;

    // ---- Q fragments (scale 1/8 folded in), bf16 hi/lo, 2 k-slabs ----
    bf16x8 qh[2], ql[2];
    {
        const float* qp = Q + ((size_t)bh * Tt + qbase + fr) * HD;
        #pragma unroll
        for (int s = 0; s < 2; ++s) {
            float4 a = *(const float4*)(qp + s * 32 + hi8 * 8);
            float4 b = *(const float4*)(qp + s * 32 + hi8 * 8 + 4);
            a.x *= 0.125f; a.y *= 0.125f; a.z *= 0.125f; a.w *= 0.125f;
            b.x *= 0.125f; b.y *= 0.125f; b.z *= 0.125f; b.w *= 0.125f;
            split8(a, b, qh[s], ql[s]);
        }
    }

    f32x4 acc_o[4];
    #pragma unroll
    for (int n = 0; n < 4; ++n) acc_o[n] = (f32x4){0.f, 0.f, 0.f, 0.f};
    float mreg[4] = {-INFINITY, -INFINITY, -INFINITY, -INFINITY};
    float lreg[4] = {0.f, 0.f, 0.f, 0.f};

    // staging mapping: thread -> (row sr, 16-col chunk sc); pure copies.
    const int sr = tid >> 2;
    const int sc = (tid & 3) * 16;
    const unsigned short* khg = Khi_g  + ((size_t)bh * Tt + sr) * HD + sc;
    const unsigned short* klg = Klo_g  + ((size_t)bh * Tt + sr) * HD + sc;
    const unsigned short* vhg = Vthi_g + ((size_t)bh * HD + sr) * Tt + sc;
    const unsigned short* vlg = Vtlo_g + ((size_t)bh * HD + sr) * Tt + sc;

    // register prefetch buffers (static indexing only)
    uint4 rkh[2], rkl[2], rvh[2], rvl[2];
    {
        #pragma unroll
        for (int h = 0; h < 2; ++h) {
            rkh[h] = *(const uint4*)(khg + h * 8);
            rkl[h] = *(const uint4*)(klg + h * 8);
            rvh[h] = *(const uint4*)(vhg + h * 8);
            rvl[h] = *(const uint4*)(vlg + h * 8);
        }
    }

    for (int ki = 0; ki <= qi; ++ki) {
        // write prefetched regs -> swizzled LDS (prev iter's end barrier
        // guarantees all reads of the old tile completed)
        #pragma unroll
        for (int h = 0; h < 2; ++h) {
            int off = (sc * 2 + h * 16) ^ ((sr & 7) << 4);
            *(uint4*)((char*)Khi  + sr * 128 + off) = rkh[h];
            *(uint4*)((char*)Klo  + sr * 128 + off) = rkl[h];
            *(uint4*)((char*)Vthi + sr * 128 + off) = rvh[h];
            *(uint4*)((char*)Vtlo + sr * 128 + off) = rvl[h];
        }
        __syncthreads();

        // issue next tile's loads NOW; they complete during compute below
        if (ki < qi) {
            const size_t ko = (size_t)(ki + 1) * 64 * HD;
            const size_t vo = (size_t)(ki + 1) * 64;
            #pragma unroll
            for (int h = 0; h < 2; ++h) {
                rkh[h] = *(const uint4*)(khg + ko + h * 8);
                rkl[h] = *(const uint4*)(klg + ko + h * 8);
                rvh[h] = *(const uint4*)(vhg + vo + h * 8);
                rvl[h] = *(const uint4*)(vlg + vo + h * 8);
            }
        }

        // ---- S = Q·K^T (bf16x3): lane holds S[q=hi8*4+i][kcol=n*16+fr] ----
        f32x4 acc_s[4];
        #pragma unroll
        for (int n = 0; n < 4; ++n) acc_s[n] = (f32x4){0.f, 0.f, 0.f, 0.f};
        #pragma unroll
        for (int n = 0; n < 4; ++n) {
            int row = n * 16 + fr;
            const char* kh_ = (const char*)Khi + row * 128;
            const char* kl_ = (const char*)Klo + row * 128;
            #pragma unroll
            for (int s = 0; s < 2; ++s) {
                int off = (s * 64 + hi8 * 16) ^ ((row & 7) << 4);
                bf16x8 kh = *(const bf16x8*)(kh_ + off);
                bf16x8 kl = *(const bf16x8*)(kl_ + off);
                acc_s[n] = __builtin_amdgcn_mfma_f32_16x16x32_bf16(qh[s], kh, acc_s[n], 0, 0, 0);
                acc_s[n] = __builtin_amdgcn_mfma_f32_16x16x32_bf16(qh[s], kl, acc_s[n], 0, 0, 0);
                acc_s[n] = __builtin_amdgcn_mfma_f32_16x16x32_bf16(ql[s], kh, acc_s[n], 0, 0, 0);
            }
        }

        // ---- causal mask (diagonal tile only; branch wave-uniform) ----
        if (ki == qi) {
            #pragma unroll
            for (int n = 0; n < 4; ++n)
                #pragma unroll
                for (int i = 0; i < 4; ++i) {
                    int kc = ki * 64 + n * 16 + fr;
                    int qr = qbase + hi8 * 4 + i;
                    if (kc > qr) acc_s[n][i] = -INFINITY;
                }
        }

        // ---- online softmax (row reduce across the 16 fr-lanes) ----
        float tmax[4], scl[4], ps[4][4];
        #pragma unroll
        for (int i = 0; i < 4; ++i)
            tmax[i] = fmaxf(fmaxf(acc_s[0][i], acc_s[1][i]),
                            fmaxf(acc_s[2][i], acc_s[3][i]));
        #pragma unroll
        for (int i = 0; i < 4; ++i) {
            tmax[i] = fmaxf(tmax[i], __shfl_xor(tmax[i], 1));
            tmax[i] = fmaxf(tmax[i], __shfl_xor(tmax[i], 2));
            tmax[i] = fmaxf(tmax[i], __shfl_xor(tmax[i], 4));
            tmax[i] = fmaxf(tmax[i], __shfl_xor(tmax[i], 8));
        }
        #pragma unroll
        for (int i = 0; i < 4; ++i) {
            float mn = fmaxf(mreg[i], tmax[i]);
            scl[i]  = __expf(mreg[i] - mn);
            mreg[i] = mn;
        }
        #pragma unroll
        for (int n = 0; n < 4; ++n)
            #pragma unroll
            for (int i = 0; i < 4; ++i)
                ps[n][i] = __expf(acc_s[n][i] - mreg[i]);
        #pragma unroll
        for (int i = 0; i < 4; ++i) {
            float r = ps[0][i] + ps[1][i] + ps[2][i] + ps[3][i];
            r += __shfl_xor(r, 1);
            r += __shfl_xor(r, 2);
            r += __shfl_xor(r, 4);
            r += __shfl_xor(r, 8);
            lreg[i] = lreg[i] * scl[i] + r;
        }
        #pragma unroll
        for (int n = 0; n < 4; ++n)
            #pragma unroll
            for (int i = 0; i < 4; ++i)
                acc_o[n][i] *= scl[i];

        // ---- P: C-layout -> A-frag layout via per-wave LDS ----
        #pragma unroll
        for (int n = 0; n < 4; ++n)
            #pragma unroll
            for (int i = 0; i < 4; ++i)
                Ppk[w][hi8 * 4 + i][n * 16 + fr] = packbf2(ps[n][i]);

        bf16x8 pah[2], pal[2];
        #pragma unroll
        for (int s = 0; s < 2; ++s) {
            const unsigned int* pr = &Ppk[w][fr][s * 32 + hi8 * 8];
            uint4 u0 = *(const uint4*)pr;
            uint4 u1 = *(const uint4*)(pr + 4);
            unsigned int uu[8] = {u0.x, u0.y, u0.z, u0.w, u1.x, u1.y, u1.z, u1.w};
            #pragma unroll
            for (int e = 0; e < 8; ++e) {
                pah[s][e] = (short)(uu[e] & 0xffffu);
                pal[s][e] = (short)(uu[e] >> 16);
            }
        }

        // ---- O += P·V (bf16x3), Vt rows = d, k-contiguous ----
        #pragma unroll
        for (int n = 0; n < 4; ++n) {
            int row = n * 16 + fr;
            const char* vh_ = (const char*)Vthi + row * 128;
            const char* vl_ = (const char*)Vtlo + row * 128;
            #pragma unroll
            for (int s = 0; s < 2; ++s) {
                int off = (s * 64 + hi8 * 16) ^ ((row & 7) << 4);
                bf16x8 vh = *(const bf16x8*)(vh_ + off);
                bf16x8 vl = *(const bf16x8*)(vl_ + off);
                acc_o[n] = __builtin_amdgcn_mfma_f32_16x16x32_bf16(pah[s], vh, acc_o[n], 0, 0, 0);
                acc_o[n] = __builtin_amdgcn_mfma_f32_16x16x32_bf16(pah[s], vl, acc_o[n], 0, 0, 0);
                acc_o[n] = __builtin_amdgcn_mfma_f32_16x16x32_bf16(pal[s], vh, acc_o[n], 0, 0, 0);
            }
        }
        __syncthreads();   // all LDS reads done before next iter's writes
    }

    // ---- epilogue: O/l, pack bf16 hi|lo, write into Q buffer slot ----
    float invl[4];
    #pragma unroll
    for (int i = 0; i < 4; ++i) invl[i] = 1.0f / lreg[i];
    unsigned int* op = Opk + ((size_t)bh * Tt + qbase) * HD;
    #pragma unroll
    for (int n = 0; n < 4; ++n)
        #pragma unroll
        for (int i = 0; i < 4; ++i)
            op[(size_t)(hi8 * 4 + i) * HD + n * 16 + fr] =
                packbf2(acc_o[n][i] * invl[i]);
}

// ---------------------------------------------------------------------------
// Kernel 3: Out[8192,1024] = O * Wout^T, bf16x3 MFMA. A operand unpacked from
// packed hi|lo uint32 in [B][H][T][64] order. XCD swizzle (512 % 8 == 0).
// ---------------------------------------------------------------------------
__global__ __launch_bounds__(256) void gemm_out_mfma(
    const unsigned int* __restrict__ Opk,
    const short* __restrict__ WOhi, const short* __restrict__ WOlo,
    float* __restrict__ Out)
{
    __shared__ __align__(16) short Ah[4096], Al[4096], Bh[4096], Bl[4096];
    const int tid = threadIdx.x;
    // XCD swizzle: chunk = 512/8 = 64.
    const int d_  = (int)blockIdx.y * (int)gridDim.x + (int)blockIdx.x;
    const int wid = (d_ & 7) * 64 + (d_ >> 3);
    const int bm  = (wid / 8) * 128;
    const int bn  = (wid % 8) * 128;
    const int w   = tid >> 6, l = tid & 63;
    const int wr  = w >> 1,  wc = w & 1;

    const int r0 = tid >> 2;
    const int c8 = (tid & 3) * 8;
    const int rA0 = bm + r0, rA1 = bm + r0 + 64;
    const int b0 = rA0 >> 11, t0 = rA0 & 2047;
    const int b1 = rA1 >> 11, t1 = rA1 & 2047;
    const size_t gb0 = (size_t)(bn + r0) * 1024 + c8;
    const size_t gb1 = (size_t)(bn + r0 + 64) * 1024 + c8;

    f32x4 acc[4][4];
    #pragma unroll
    for (int m = 0; m < 4; ++m)
        #pragma unroll
        for (int n = 0; n < 4; ++n) acc[m][n] = (f32x4){0.f, 0.f, 0.f, 0.f};

    uint4 ua0, ua1, ua2, ua3;
    float4 pbh0, pbh1, pbl0, pbl1;
    {
        int c = c8;
        int hh = c >> 6, d = c & 63;
        size_t ia0 = ((size_t)(b0 * NH + hh) * Tt + t0) * 64 + d;
        size_t ia1 = ((size_t)(b1 * NH + hh) * Tt + t1) * 64 + d;
        ua0 = *(const uint4*)(Opk + ia0);  ua1 = *(const uint4*)(Opk + ia0 + 4);
        ua2 = *(const uint4*)(Opk + ia1);  ua3 = *(const uint4*)(Opk + ia1 + 4);
        pbh0 = *(const float4*)(WOhi + gb0);
        pbh1 = *(const float4*)(WOhi + gb1);
        pbl0 = *(const float4*)(WOlo + gb0);
        pbl1 = *(const float4*)(WOlo + gb1);
    }

    for (int k0 = 0; k0 < 1024; k0 += 32) {
        __syncthreads();
        {
            bf16x8 H, L;
            H[0] = (short)ua0.x; L[0] = (short)(ua0.x >> 16);
            H[1] = (short)ua0.y; L[1] = (short)(ua0.y >> 16);
            H[2] = (short)ua0.z; L[2] = (short)(ua0.z >> 16);
            H[3] = (short)ua0.w; L[3] = (short)(ua0.w >> 16);
            H[4] = (short)ua1.x; L[4] = (short)(ua1.x >> 16);
            H[5] = (short)ua1.y; L[5] = (short)(ua1.y >> 16);
            H[6] = (short)ua1.z; L[6] = (short)(ua1.z >> 16);
            H[7] = (short)ua1.w; L[7] = (short)(ua1.w >> 16);
            *(bf16x8*)&Ah[tid * 8] = H;  *(bf16x8*)&Al[tid * 8] = L;
            H[0] = (short)ua2.x; L[0] = (short)(ua2.x >> 16);
            H[1] = (short)ua2.y; L[1] = (short)(ua2.y >> 16);
            H[2] = (short)ua2.z; L[2] = (short)(ua2.z >> 16);
            H[3] = (short)ua2.w; L[3] = (short)(ua2.w >> 16);
            H[4] = (short)ua3.x; L[4] = (short)(ua3.x >> 16);
            H[5] = (short)ua3.y; L[5] = (short)(ua3.y >> 16);
            H[6] = (short)ua3.z; L[6] = (short)(ua3.z >> 16);
            H[7] = (short)ua3.w; L[7] = (short)(ua3.w >> 16);
            *(bf16x8*)&Ah[(tid + 256) * 8] = H;  *(bf16x8*)&Al[(tid + 256) * 8] = L;
        }
        *(float4*)&Bh[tid * 8] = pbh0;  *(float4*)&Bh[(tid + 256) * 8] = pbh1;
        *(float4*)&Bl[tid * 8] = pbl0;  *(float4*)&Bl[(tid + 256) * 8] = pbl1;

        int kn = (k0 + 32) & 1023;
        {
            int c = kn + c8;
            int hh = c >> 6, d = c & 63;
            size_t ia0 = ((size_t)(b0 * NH + hh) * Tt + t0) * 64 + d;
            size_t ia1 = ((size_t)(b1 * NH + hh) * Tt + t1) * 64 + d;
            ua0 = *(const uint4*)(Opk + ia0);  ua1 = *(const uint4*)(Opk + ia0 + 4);
            ua2 = *(const uint4*)(Opk + ia1);  ua3 = *(const uint4*)(Opk + ia1 + 4);
            pbh0 = *(const float4*)(WOhi + gb0 + kn);
            pbh1 = *(const float4*)(WOhi + gb1 + kn);
            pbl0 = *(const float4*)(WOlo + gb0 + kn);
            pbl1 = *(const float4*)(WOlo + gb1 + kn);
        }
        __syncthreads();

        const int fr = l & 15;
        const int fg = (l >> 4) * 8;
        bf16x8 ah[4], alo[4], bhv[4], blo[4];
        #pragma unroll
        for (int m = 0; m < 4; ++m) {
            int ro = (wr * 64 + m * 16 + fr) * 32 + fg;
            ah[m]  = *(const bf16x8*)&Ah[ro];
            alo[m] = *(const bf16x8*)&Al[ro];
        }
        #pragma unroll
        for (int n = 0; n < 4; ++n) {
            int ro = (wc * 64 + n * 16 + fr) * 32 + fg;
            bhv[n] = *(const bf16x8*)&Bh[ro];
            blo[n] = *(const bf16x8*)&Bl[ro];
        }
        #pragma unroll
        for (int m = 0; m < 4; ++m)
            #pragma unroll
            for (int n = 0; n < 4; ++n) {
                acc[m][n] = __builtin_amdgcn_mfma_f32_16x16x32_bf16(ah[m],  bhv[n], acc[m][n], 0, 0, 0);
                acc[m][n] = __builtin_amdgcn_mfma_f32_16x16x32_bf16(ah[m],  blo[n], acc[m][n], 0, 0, 0);
                acc[m][n] = __builtin_amdgcn_mfma_f32_16x16x32_bf16(alo[m], bhv[n], acc[m][n], 0, 0, 0);
            }
    }

    const int fr = l & 15, fq = l >> 4;
    #pragma unroll
    for (int m = 0; m < 4; ++m)
        #pragma unroll
        for (int n = 0; n < 4; ++n) {
            int col = bn + wc * 64 + n * 16 + fr;
            #pragma unroll
            for (int i = 0; i < 4; ++i) {
                int r = bm + wr * 64 + m * 16 + fq * 4 + i;
                Out[(size_t)r * 1024 + col] = acc[m][n][i];
            }
        }
}

// ---------------------------------------------------------------------------
extern "C" void kernel_launch(void* const* d_in, const int* in_sizes, int n_in,
                              void* d_out, int out_size, void* d_ws, size_t ws_size,
                              hipStream_t stream)
{
    const float* x    = (const float*)d_in[0];   // (4, 2048, 1024)
    const float* wqkv = (const float*)d_in[1];   // (3072, 1024)
    const float* wout = (const float*)d_in[2];   // (1024, 1024)
    float* out = (float*)d_out;

    // ws layout (<=113 MB):
    //   [0,32M):   Q fp32  -> later packed O (bf16 hi|lo per uint32, same idx)
    //   [32,48M):  Khi bf16 [bh][t][d]    [48,64M): Klo
    //   [64,80M):  Vthi bf16 [bh][d][t]   [80,96M): Vtlo
    //   [96,102M): Wqkv hi   [102,108M): Wqkv lo
    //   [108,110M): Wout hi  [110,112M): Wout lo
    //   [112M,+512K): rope table
    // d_out (32 MB) holds Xhi/Xlo until gemm_out overwrites it.
    char* wsb = (char*)d_ws;
    float*          Qf   = (float*)(wsb);
    unsigned int*   Opk  = (unsigned int*)(wsb);
    unsigned short* Khig = (unsigned short*)(wsb + (size_t)32 * 1048576);
    unsigned short* Klog = (unsigned short*)(wsb + (size_t)48 * 1048576);
    unsigned short* Vthig= (unsigned short*)(wsb + (size_t)64 * 1048576);
    unsigned short* Vtlog= (unsigned short*)(wsb + (size_t)80 * 1048576);
    short*          Whi  = (short*)(wsb + (size_t)96  * 1048576);
    short*          Wlo  = (short*)(wsb + (size_t)102 * 1048576);
    short*          WOhi = (short*)(wsb + (size_t)108 * 1048576);
    short*          WOlo = (short*)(wsb + (size_t)110 * 1048576);
    float*          tab  = (float*)(wsb + (size_t)112 * 1048576);

    short* Xhi = (short*)d_out;
    short* Xlo = (short*)d_out + 8388608;

    rope_table<<<256, 256, 0, stream>>>(tab);
    cast_split<<<8192, 256, 0, stream>>>(x,    Xhi,  Xlo,  2097152);
    cast_split<<<3072, 256, 0, stream>>>(wqkv, Whi,  Wlo,  786432);
    cast_split<<<1024, 256, 0, stream>>>(wout, WOhi, WOlo, 262144);

    dim3 g1(24, 64);
    gemm_qkv_mfma<<<g1, 256, 0, stream>>>(Xhi, Xlo, Whi, Wlo, tab, Qf,
                                          Khig, Klog, Vthig, Vtlog);

    dim3 g2(32, 64);
    attn_fwd_mfma<<<g2, 256, 0, stream>>>(Qf, Khig, Klog, Vthig, Vtlog, Opk);

    dim3 g3(8, 64);
    gemm_out_mfma<<<g3, 256, 0, stream>>>(Opk, WOhi, WOlo, out);
}

// Round 11
// 687.044 us; speedup vs baseline: 1.4376x; 1.4376x over previous
//
#include <hip/hip_runtime.h>
#include <hip/hip_bf16.h>
#include <math.h>

// Problem constants
constexpr int Bb  = 4;
constexpr int Tt  = 2048;
constexpr int DM  = 1024;
constexpr int NH  = 16;
constexpr int HD  = 64;
constexpr int MBT = Bb * Tt;                       // 8192
constexpr float LOG_THETA = 9.210340371976184f;    // ln(10000)

using bf16x8 = __attribute__((ext_vector_type(8))) short;   // 8 bf16 (4 VGPRs)
using f32x4  = __attribute__((ext_vector_type(4))) float;   // MFMA accumulator

__device__ inline short f2bf(float x) {
    __hip_bfloat16 h = __float2bfloat16(x);
    return *reinterpret_cast<short*>(&h);
}
__device__ inline float bf2f(short u) {
    __hip_bfloat16 h;
    *reinterpret_cast<short*>(&h) = u;
    return __bfloat162float(h);
}
__device__ inline unsigned int packbf2(float x) {
    short h  = f2bf(x);
    short lo = f2bf(x - bf2f(h));
    return (unsigned int)(unsigned short)h | ((unsigned int)(unsigned short)lo << 16);
}
// 8 fp32 -> bf16 hi/lo vectors (all indices static after unroll)
__device__ inline void split8(float4 a, float4 b, bf16x8& H, bf16x8& L) {
    float x[8] = {a.x, a.y, a.z, a.w, b.x, b.y, b.z, b.w};
    #pragma unroll
    for (int e = 0; e < 8; ++e) {
        short h = f2bf(x[e]);
        H[e] = h;
        L[e] = f2bf(x[e] - bf2f(h));
    }
}

// ---------------------------------------------------------------------------
// RoPE cos/sin table: tab[t*64 + 2p] = cos(t*theta^(-2p/64)), +1 = sin.
// ---------------------------------------------------------------------------
__global__ __launch_bounds__(256) void rope_table(float* __restrict__ tab)
{
    int i = blockIdx.x * 256 + threadIdx.x;   // 0..65535
    int t = i >> 5, p = i & 31;
    float freq = expf(-(float)(2 * p) * (LOG_THETA / 64.0f));
    float ang  = (float)t * freq;
    tab[t * 64 + 2 * p]     = cosf(ang);
    tab[t * 64 + 2 * p + 1] = sinf(ang);
}

// ---------------------------------------------------------------------------
// fp32 -> bf16 hi/lo split arrays. 4 elems/thread.
// ---------------------------------------------------------------------------
__global__ __launch_bounds__(256) void cast_split(
    const float* __restrict__ src, short* __restrict__ hi,
    short* __restrict__ lo, int n4)
{
    int i = blockIdx.x * 256 + threadIdx.x;
    if (i >= n4) return;
    float4 v = reinterpret_cast<const float4*>(src)[i];
    short h0 = f2bf(v.x), h1 = f2bf(v.y), h2 = f2bf(v.z), h3 = f2bf(v.w);
    short l0 = f2bf(v.x - bf2f(h0));
    short l1 = f2bf(v.y - bf2f(h1));
    short l2 = f2bf(v.z - bf2f(h2));
    short l3 = f2bf(v.w - bf2f(h3));
    reinterpret_cast<short4*>(hi)[i] = make_short4(h0, h1, h2, h3);
    reinterpret_cast<short4*>(lo)[i] = make_short4(l0, l1, l2, l3);
}

// ---------------------------------------------------------------------------
// Kernel 1: QKV GEMM via bf16x3 MFMA (~fp32 precision).
// C[8192,3072] = X * Wqkv^T. 128x128 tile, BK=32, 4 waves (2x2), 4x4 frags.
// XCD-aware swizzle (T1): 1536 blocks % 8 == 0, bijective chunk remap.
// Epilogue: RoPE + scatter (Q fp32; K, Vt pre-split bf16 hi/lo; Vt transposed).
// ---------------------------------------------------------------------------
__global__ __launch_bounds__(256) void gemm_qkv_mfma(
    const short* __restrict__ Xhi, const short* __restrict__ Xlo,
    const short* __restrict__ Whi, const short* __restrict__ Wlo,
    const float* __restrict__ tab,
    float* __restrict__ Qo,
    unsigned short* __restrict__ Khi_g, unsigned short* __restrict__ Klo_g,
    unsigned short* __restrict__ Vthi_g, unsigned short* __restrict__ Vtlo_g)
{
    __shared__ __align__(16) short Ah[4096], Al[4096], Bh[4096], Bl[4096];
    const int tid = threadIdx.x;
    const int d_  = (int)blockIdx.y * (int)gridDim.x + (int)blockIdx.x;
    const int wid = (d_ & 7) * 192 + (d_ >> 3);
    const int bm  = (wid / 24) * 128;
    const int bn  = (wid % 24) * 128;
    const int w   = tid >> 6, l = tid & 63;
    const int wr  = w >> 1,  wc = w & 1;

    const int r0 = tid >> 2;
    const int c0 = (tid & 3) * 8;
    const size_t ga0 = (size_t)(bm + r0) * 1024 + c0;
    const size_t ga1 = (size_t)(bm + r0 + 64) * 1024 + c0;
    const size_t gb0 = (size_t)(bn + r0) * 1024 + c0;
    const size_t gb1 = (size_t)(bn + r0 + 64) * 1024 + c0;

    f32x4 acc[4][4];
    #pragma unroll
    for (int m = 0; m < 4; ++m)
        #pragma unroll
        for (int n = 0; n < 4; ++n) acc[m][n] = (f32x4){0.f, 0.f, 0.f, 0.f};

    float4 pah0 = *(const float4*)(Xhi + ga0);
    float4 pah1 = *(const float4*)(Xhi + ga1);
    float4 pal0 = *(const float4*)(Xlo + ga0);
    float4 pal1 = *(const float4*)(Xlo + ga1);
    float4 pbh0 = *(const float4*)(Whi + gb0);
    float4 pbh1 = *(const float4*)(Whi + gb1);
    float4 pbl0 = *(const float4*)(Wlo + gb0);
    float4 pbl1 = *(const float4*)(Wlo + gb1);

    for (int k0 = 0; k0 < 1024; k0 += 32) {
        __syncthreads();
        *(float4*)&Ah[tid * 8] = pah0;  *(float4*)&Ah[(tid + 256) * 8] = pah1;
        *(float4*)&Al[tid * 8] = pal0;  *(float4*)&Al[(tid + 256) * 8] = pal1;
        *(float4*)&Bh[tid * 8] = pbh0;  *(float4*)&Bh[(tid + 256) * 8] = pbh1;
        *(float4*)&Bl[tid * 8] = pbl0;  *(float4*)&Bl[(tid + 256) * 8] = pbl1;
        int kn = (k0 + 32) & 1023;
        pah0 = *(const float4*)(Xhi + ga0 + kn);
        pah1 = *(const float4*)(Xhi + ga1 + kn);
        pal0 = *(const float4*)(Xlo + ga0 + kn);
        pal1 = *(const float4*)(Xlo + ga1 + kn);
        pbh0 = *(const float4*)(Whi + gb0 + kn);
        pbh1 = *(const float4*)(Whi + gb1 + kn);
        pbl0 = *(const float4*)(Wlo + gb0 + kn);
        pbl1 = *(const float4*)(Wlo + gb1 + kn);
        __syncthreads();

        const int fr = l & 15;
        const int fg = (l >> 4) * 8;
        bf16x8 ah[4], alo[4], bhv[4], blo[4];
        #pragma unroll
        for (int m = 0; m < 4; ++m) {
            int ro = (wr * 64 + m * 16 + fr) * 32 + fg;
            ah[m]  = *(const bf16x8*)&Ah[ro];
            alo[m] = *(const bf16x8*)&Al[ro];
        }
        #pragma unroll
        for (int n = 0; n < 4; ++n) {
            int ro = (wc * 64 + n * 16 + fr) * 32 + fg;
            bhv[n] = *(const bf16x8*)&Bh[ro];
            blo[n] = *(const bf16x8*)&Bl[ro];
        }
        #pragma unroll
        for (int m = 0; m < 4; ++m)
            #pragma unroll
            for (int n = 0; n < 4; ++n) {
                acc[m][n] = __builtin_amdgcn_mfma_f32_16x16x32_bf16(ah[m],  bhv[n], acc[m][n], 0, 0, 0);
                acc[m][n] = __builtin_amdgcn_mfma_f32_16x16x32_bf16(ah[m],  blo[n], acc[m][n], 0, 0, 0);
                acc[m][n] = __builtin_amdgcn_mfma_f32_16x16x32_bf16(alo[m], bhv[n], acc[m][n], 0, 0, 0);
            }
    }

    // Epilogue: C/D layout col = lane&15, row = (lane>>4)*4 + reg (m89).
    const int fr = l & 15, fq = l >> 4;
    #pragma unroll
    for (int m = 0; m < 4; ++m) {
        #pragma unroll
        for (int n = 0; n < 4; ++n) {
            int col  = bn + wc * 64 + n * 16 + fr;
            int sect = col >> 10;          // 0=q 1=k 2=v (wave-uniform)
            int cc   = col & 1023;
            int hh   = cc >> 6, d = cc & 63;
            int de   = d & 62;
            #pragma unroll
            for (int i = 0; i < 4; ++i) {
                int r  = bm + wr * 64 + m * 16 + fq * 4 + i;
                int b_ = r >> 11, t_ = r & 2047;
                float v  = acc[m][n][i];
                float vn = __shfl_xor(v, 1);
                if (sect == 2) {
                    size_t off = ((size_t)(b_ * NH + hh) * HD + d) * Tt + t_;
                    short h = f2bf(v);
                    Vthi_g[off] = (unsigned short)h;
                    Vtlo_g[off] = (unsigned short)f2bf(v - bf2f(h));
                } else {
                    float2 cssn = *(const float2*)(tab + t_ * 64 + de);
                    float outv = (d & 1) ? (vn * cssn.y + v * cssn.x)
                                         : (v * cssn.x - vn * cssn.y);
                    size_t off = ((size_t)(b_ * NH + hh) * Tt + t_) * HD + d;
                    if (sect == 0) {
                        Qo[off] = outv;
                    } else {
                        short h = f2bf(outv);
                        Khi_g[off] = (unsigned short)h;
                        Klo_g[off] = (unsigned short)f2bf(outv - bf2f(h));
                    }
                }
            }
        }
    }
}

// ---------------------------------------------------------------------------
// Kernel 2: causal flash attention, MFMA bf16-hi/lo x3 (~fp32 precision).
// FATTENED: 128 q-rows per block (wave owns 32 rows = 2 m-frags) -> staging
// events and K/V re-reads HALVE vs 64-row blocks; same total MFMA work.
// Grid (16, B*H); qi = 15 - blockIdx.x (longest-first).
// Staging = R7's verified serial uint4 copy into XOR-swizzled LDS
// (byte^=(row&7)<<4).  NO register prefetch (R9's spilled -> 380MB scratch).
// Softmax/P/PV sequenced per m-frag to bound register liveness; Ppk buffer
// reused across the two passes (LDS stays 50176B -> 3 blocks/CU).
// ---------------------------------------------------------------------------
__global__ __launch_bounds__(256) void attn_fwd_mfma(
    const float* Q,
    const unsigned short* __restrict__ Khi_g, const unsigned short* __restrict__ Klo_g,
    const unsigned short* __restrict__ Vthi_g, const unsigned short* __restrict__ Vtlo_g,
    unsigned int* Opk)
{
    __shared__ __align__(16) short Khi[4096], Klo[4096], Vthi[4096], Vtlo[4096];
    __shared__ __align__(16) unsigned int Ppk[4][16][68];   // per-wave, reused per m

    const int tid = threadIdx.x;
    const int w   = tid >> 6;
    const int l   = tid & 63;
    const int fr  = l & 15;
    const int hi8 = l >> 4;
    const int bh  = blockIdx.y;
    const int qi  = (int)gridDim.x - 1 - (int)blockIdx.x;   // longest-first
    const int qbase = qi * 128 + w * 32;                    // wave's first q-row

    // ---- Q fragments (scale 1/8 folded), 2 m-frags x 2 k-slabs ----
    bf16x8 qh[2][2], ql[2][2];
    #pragma unroll
    for (int m = 0; m < 2; ++m) {
        const float* qp = Q + ((size_t)bh * Tt + qbase + m * 16 + fr) * HD;
        #pragma unroll
        for (int s = 0; s < 2; ++s) {
            float4 a = *(const float4*)(qp + s * 32 + hi8 * 8);
            float4 b = *(const float4*)(qp + s * 32 + hi8 * 8 + 4);
            a.x *= 0.125f; a.y *= 0.125f; a.z *= 0.125f; a.w *= 0.125f;
            b.x *= 0.125f; b.y *= 0.125f; b.z *= 0.125f; b.w *= 0.125f;
            split8(a, b, qh[m][s], ql[m][s]);
        }
    }

    f32x4 acc_o[2][4];
    #pragma unroll
    for (int m = 0; m < 2; ++m)
        #pragma unroll
        for (int n = 0; n < 4; ++n) acc_o[m][n] = (f32x4){0.f, 0.f, 0.f, 0.f};
    float mreg[2][4], lreg[2][4];
    #pragma unroll
    for (int m = 0; m < 2; ++m)
        #pragma unroll
        for (int i = 0; i < 4; ++i) { mreg[m][i] = -INFINITY; lreg[m][i] = 0.f; }

    // staging mapping: thread -> (row sr, 16-col chunk sc); pure copies.
    const int sr = tid >> 2;
    const int sc = (tid & 3) * 16;
    const unsigned short* khg = Khi_g  + ((size_t)bh * Tt + sr) * HD + sc;
    const unsigned short* klg = Klo_g  + ((size_t)bh * Tt + sr) * HD + sc;
    const unsigned short* vhg = Vthi_g + ((size_t)bh * HD + sr) * Tt + sc;
    const unsigned short* vlg = Vtlo_g + ((size_t)bh * HD + sr) * Tt + sc;

    const int ktiles = 2 * qi + 2;
    for (int ki = 0; ki < ktiles; ++ki) {
        __syncthreads();   // previous tile's LDS reads complete
        {
            const size_t ko = (size_t)ki * 64 * HD;
            const size_t vo = (size_t)ki * 64;
            #pragma unroll
            for (int h = 0; h < 2; ++h) {
                int off = (sc * 2 + h * 16) ^ ((sr & 7) << 4);
                *(uint4*)((char*)Khi  + sr * 128 + off) = *(const uint4*)(khg + ko + h * 8);
                *(uint4*)((char*)Klo  + sr * 128 + off) = *(const uint4*)(klg + ko + h * 8);
                *(uint4*)((char*)Vthi + sr * 128 + off) = *(const uint4*)(vhg + vo + h * 8);
                *(uint4*)((char*)Vtlo + sr * 128 + off) = *(const uint4*)(vlg + vo + h * 8);
            }
        }
        __syncthreads();

        // ---- S = Q·K^T for BOTH m-frags (K frag read once, used twice) ----
        f32x4 acc_s[2][4];
        #pragma unroll
        for (int m = 0; m < 2; ++m)
            #pragma unroll
            for (int n = 0; n < 4; ++n) acc_s[m][n] = (f32x4){0.f, 0.f, 0.f, 0.f};
        #pragma unroll
        for (int n = 0; n < 4; ++n) {
            int row = n * 16 + fr;
            const char* kh_ = (const char*)Khi + row * 128;
            const char* kl_ = (const char*)Klo + row * 128;
            #pragma unroll
            for (int s = 0; s < 2; ++s) {
                int off = (s * 64 + hi8 * 16) ^ ((row & 7) << 4);
                bf16x8 kh = *(const bf16x8*)(kh_ + off);
                bf16x8 kl = *(const bf16x8*)(kl_ + off);
                #pragma unroll
                for (int m = 0; m < 2; ++m) {
                    acc_s[m][n] = __builtin_amdgcn_mfma_f32_16x16x32_bf16(qh[m][s], kh, acc_s[m][n], 0, 0, 0);
                    acc_s[m][n] = __builtin_amdgcn_mfma_f32_16x16x32_bf16(qh[m][s], kl, acc_s[m][n], 0, 0, 0);
                    acc_s[m][n] = __builtin_amdgcn_mfma_f32_16x16x32_bf16(ql[m][s], kh, acc_s[m][n], 0, 0, 0);
                }
            }
        }

        // ---- causal mask (last two tiles only; block-uniform branch) ----
        if (ki >= 2 * qi) {
            #pragma unroll
            for (int m = 0; m < 2; ++m)
                #pragma unroll
                for (int n = 0; n < 4; ++n)
                    #pragma unroll
                    for (int i = 0; i < 4; ++i) {
                        int kc = ki * 64 + n * 16 + fr;
                        int qr = qbase + m * 16 + hi8 * 4 + i;
                        if (kc > qr) acc_s[m][n][i] = -INFINITY;
                    }
        }

        // ---- per m-frag: softmax -> P relayout -> PV (bounds liveness) ----
        #pragma unroll
        for (int m = 0; m < 2; ++m) {
            float tmax[4], scl[4], ps[4][4];
            #pragma unroll
            for (int i = 0; i < 4; ++i)
                tmax[i] = fmaxf(fmaxf(acc_s[m][0][i], acc_s[m][1][i]),
                                fmaxf(acc_s[m][2][i], acc_s[m][3][i]));
            #pragma unroll
            for (int i = 0; i < 4; ++i) {
                tmax[i] = fmaxf(tmax[i], __shfl_xor(tmax[i], 1));
                tmax[i] = fmaxf(tmax[i], __shfl_xor(tmax[i], 2));
                tmax[i] = fmaxf(tmax[i], __shfl_xor(tmax[i], 4));
                tmax[i] = fmaxf(tmax[i], __shfl_xor(tmax[i], 8));
            }
            #pragma unroll
            for (int i = 0; i < 4; ++i) {
                float mn = fmaxf(mreg[m][i], tmax[i]);
                scl[i]     = __expf(mreg[m][i] - mn);
                mreg[m][i] = mn;
            }
            #pragma unroll
            for (int n = 0; n < 4; ++n)
                #pragma unroll
                for (int i = 0; i < 4; ++i)
                    ps[n][i] = __expf(acc_s[m][n][i] - mreg[m][i]);
            #pragma unroll
            for (int i = 0; i < 4; ++i) {
                float r = ps[0][i] + ps[1][i] + ps[2][i] + ps[3][i];
                r += __shfl_xor(r, 1);
                r += __shfl_xor(r, 2);
                r += __shfl_xor(r, 4);
                r += __shfl_xor(r, 8);
                lreg[m][i] = lreg[m][i] * scl[i] + r;
            }
            #pragma unroll
            for (int n = 0; n < 4; ++n)
                #pragma unroll
                for (int i = 0; i < 4; ++i)
                    acc_o[m][n][i] *= scl[i];

            // P: C-layout -> A-frag via per-wave LDS (same-wave, lgkmcnt-ordered)
            #pragma unroll
            for (int n = 0; n < 4; ++n)
                #pragma unroll
                for (int i = 0; i < 4; ++i)
                    Ppk[w][hi8 * 4 + i][n * 16 + fr] = packbf2(ps[n][i]);

            bf16x8 pah[2], pal[2];
            #pragma unroll
            for (int s = 0; s < 2; ++s) {
                const unsigned int* pr = &Ppk[w][fr][s * 32 + hi8 * 8];
                uint4 u0 = *(const uint4*)pr;
                uint4 u1 = *(const uint4*)(pr + 4);
                unsigned int uu[8] = {u0.x, u0.y, u0.z, u0.w, u1.x, u1.y, u1.z, u1.w};
                #pragma unroll
                for (int e = 0; e < 8; ++e) {
                    pah[s][e] = (short)(uu[e] & 0xffffu);
                    pal[s][e] = (short)(uu[e] >> 16);
                }
            }

            #pragma unroll
            for (int n = 0; n < 4; ++n) {
                int row = n * 16 + fr;
                const char* vh_ = (const char*)Vthi + row * 128;
                const char* vl_ = (const char*)Vtlo + row * 128;
                #pragma unroll
                for (int s = 0; s < 2; ++s) {
                    int off = (s * 64 + hi8 * 16) ^ ((row & 7) << 4);
                    bf16x8 vh = *(const bf16x8*)(vh_ + off);
                    bf16x8 vl = *(const bf16x8*)(vl_ + off);
                    acc_o[m][n] = __builtin_amdgcn_mfma_f32_16x16x32_bf16(pah[s], vh, acc_o[m][n], 0, 0, 0);
                    acc_o[m][n] = __builtin_amdgcn_mfma_f32_16x16x32_bf16(pah[s], vl, acc_o[m][n], 0, 0, 0);
                    acc_o[m][n] = __builtin_amdgcn_mfma_f32_16x16x32_bf16(pal[s], vh, acc_o[m][n], 0, 0, 0);
                }
            }
        }
    }

    // ---- epilogue: O/l, pack bf16 hi|lo, write into Q buffer slot ----
    unsigned int* op = Opk + ((size_t)bh * Tt + qbase) * HD;
    #pragma unroll
    for (int m = 0; m < 2; ++m) {
        float invl[4];
        #pragma unroll
        for (int i = 0; i < 4; ++i) invl[i] = 1.0f / lreg[m][i];
        #pragma unroll
        for (int n = 0; n < 4; ++n)
            #pragma unroll
            for (int i = 0; i < 4; ++i)
                op[(size_t)(m * 16 + hi8 * 4 + i) * HD + n * 16 + fr] =
                    packbf2(acc_o[m][n][i] * invl[i]);
    }
}

// ---------------------------------------------------------------------------
// Kernel 3: Out[8192,1024] = O * Wout^T, bf16x3 MFMA. A operand unpacked from
// packed hi|lo uint32 in [B][H][T][64] order. XCD swizzle (512 % 8 == 0).
// ---------------------------------------------------------------------------
__global__ __launch_bounds__(256) void gemm_out_mfma(
    const unsigned int* __restrict__ Opk,
    const short* __restrict__ WOhi, const short* __restrict__ WOlo,
    float* __restrict__ Out)
{
    __shared__ __align__(16) short Ah[4096], Al[4096], Bh[4096], Bl[4096];
    const int tid = threadIdx.x;
    const int d_  = (int)blockIdx.y * (int)gridDim.x + (int)blockIdx.x;
    const int wid = (d_ & 7) * 64 + (d_ >> 3);
    const int bm  = (wid / 8) * 128;
    const int bn  = (wid % 8) * 128;
    const int w   = tid >> 6, l = tid & 63;
    const int wr  = w >> 1,  wc = w & 1;

    const int r0 = tid >> 2;
    const int c8 = (tid & 3) * 8;
    const int rA0 = bm + r0, rA1 = bm + r0 + 64;
    const int b0 = rA0 >> 11, t0 = rA0 & 2047;
    const int b1 = rA1 >> 11, t1 = rA1 & 2047;
    const size_t gb0 = (size_t)(bn + r0) * 1024 + c8;
    const size_t gb1 = (size_t)(bn + r0 + 64) * 1024 + c8;

    f32x4 acc[4][4];
    #pragma unroll
    for (int m = 0; m < 4; ++m)
        #pragma unroll
        for (int n = 0; n < 4; ++n) acc[m][n] = (f32x4){0.f, 0.f, 0.f, 0.f};

    uint4 ua0, ua1, ua2, ua3;
    float4 pbh0, pbh1, pbl0, pbl1;
    {
        int c = c8;
        int hh = c >> 6, d = c & 63;
        size_t ia0 = ((size_t)(b0 * NH + hh) * Tt + t0) * 64 + d;
        size_t ia1 = ((size_t)(b1 * NH + hh) * Tt + t1) * 64 + d;
        ua0 = *(const uint4*)(Opk + ia0);  ua1 = *(const uint4*)(Opk + ia0 + 4);
        ua2 = *(const uint4*)(Opk + ia1);  ua3 = *(const uint4*)(Opk + ia1 + 4);
        pbh0 = *(const float4*)(WOhi + gb0);
        pbh1 = *(const float4*)(WOhi + gb1);
        pbl0 = *(const float4*)(WOlo + gb0);
        pbl1 = *(const float4*)(WOlo + gb1);
    }

    for (int k0 = 0; k0 < 1024; k0 += 32) {
        __syncthreads();
        {
            bf16x8 H, L;
            H[0] = (short)ua0.x; L[0] = (short)(ua0.x >> 16);
            H[1] = (short)ua0.y; L[1] = (short)(ua0.y >> 16);
            H[2] = (short)ua0.z; L[2] = (short)(ua0.z >> 16);
            H[3] = (short)ua0.w; L[3] = (short)(ua0.w >> 16);
            H[4] = (short)ua1.x; L[4] = (short)(ua1.x >> 16);
            H[5] = (short)ua1.y; L[5] = (short)(ua1.y >> 16);
            H[6] = (short)ua1.z; L[6] = (short)(ua1.z >> 16);
            H[7] = (short)ua1.w; L[7] = (short)(ua1.w >> 16);
            *(bf16x8*)&Ah[tid * 8] = H;  *(bf16x8*)&Al[tid * 8] = L;
            H[0] = (short)ua2.x; L[0] = (short)(ua2.x >> 16);
            H[1] = (short)ua2.y; L[1] = (short)(ua2.y >> 16);
            H[2] = (short)ua2.z; L[2] = (short)(ua2.z >> 16);
            H[3] = (short)ua2.w; L[3] = (short)(ua2.w >> 16);
            H[4] = (short)ua3.x; L[4] = (short)(ua3.x >> 16);
            H[5] = (short)ua3.y; L[5] = (short)(ua3.y >> 16);
            H[6] = (short)ua3.z; L[6] = (short)(ua3.z >> 16);
            H[7] = (short)ua3.w; L[7] = (short)(ua3.w >> 16);
            *(bf16x8*)&Ah[(tid + 256) * 8] = H;  *(bf16x8*)&Al[(tid + 256) * 8] = L;
        }
        *(float4*)&Bh[tid * 8] = pbh0;  *(float4*)&Bh[(tid + 256) * 8] = pbh1;
        *(float4*)&Bl[tid * 8] = pbl0;  *(float4*)&Bl[(tid + 256) * 8] = pbl1;

        int kn = (k0 + 32) & 1023;
        {
            int c = kn + c8;
            int hh = c >> 6, d = c & 63;
            size_t ia0 = ((size_t)(b0 * NH + hh) * Tt + t0) * 64 + d;
            size_t ia1 = ((size_t)(b1 * NH + hh) * Tt + t1) * 64 + d;
            ua0 = *(const uint4*)(Opk + ia0);  ua1 = *(const uint4*)(Opk + ia0 + 4);
            ua2 = *(const uint4*)(Opk + ia1);  ua3 = *(const uint4*)(Opk + ia1 + 4);
            pbh0 = *(const float4*)(WOhi + gb0 + kn);
            pbh1 = *(const float4*)(WOhi + gb1 + kn);
            pbl0 = *(const float4*)(WOlo + gb0 + kn);
            pbl1 = *(const float4*)(WOlo + gb1 + kn);
        }
        __syncthreads();

        const int fr = l & 15;
        const int fg = (l >> 4) * 8;
        bf16x8 ah[4], alo[4], bhv[4], blo[4];
        #pragma unroll
        for (int m = 0; m < 4; ++m) {
            int ro = (wr * 64 + m * 16 + fr) * 32 + fg;
            ah[m]  = *(const bf16x8*)&Ah[ro];
            alo[m] = *(const bf16x8*)&Al[ro];
        }
        #pragma unroll
        for (int n = 0; n < 4; ++n) {
            int ro = (wc * 64 + n * 16 + fr) * 32 + fg;
            bhv[n] = *(const bf16x8*)&Bh[ro];
            blo[n] = *(const bf16x8*)&Bl[ro];
        }
        #pragma unroll
        for (int m = 0; m < 4; ++m)
            #pragma unroll
            for (int n = 0; n < 4; ++n) {
                acc[m][n] = __builtin_amdgcn_mfma_f32_16x16x32_bf16(ah[m],  bhv[n], acc[m][n], 0, 0, 0);
                acc[m][n] = __builtin_amdgcn_mfma_f32_16x16x32_bf16(ah[m],  blo[n], acc[m][n], 0, 0, 0);
                acc[m][n] = __builtin_amdgcn_mfma_f32_16x16x32_bf16(alo[m], bhv[n], acc[m][n], 0, 0, 0);
            }
    }

    const int fr = l & 15, fq = l >> 4;
    #pragma unroll
    for (int m = 0; m < 4; ++m)
        #pragma unroll
        for (int n = 0; n < 4; ++n) {
            int col = bn + wc * 64 + n * 16 + fr;
            #pragma unroll
            for (int i = 0; i < 4; ++i) {
                int r = bm + wr * 64 + m * 16 + fq * 4 + i;
                Out[(size_t)r * 1024 + col] = acc[m][n][i];
            }
        }
}

// ---------------------------------------------------------------------------
extern "C" void kernel_launch(void* const* d_in, const int* in_sizes, int n_in,
                              void* d_out, int out_size, void* d_ws, size_t ws_size,
                              hipStream_t stream)
{
    const float* x    = (const float*)d_in[0];   // (4, 2048, 1024)
    const float* wqkv = (const float*)d_in[1];   // (3072, 1024)
    const float* wout = (const float*)d_in[2];   // (1024, 1024)
    float* out = (float*)d_out;

    // ws layout (<=113 MB):
    //   [0,32M):   Q fp32  -> later packed O (bf16 hi|lo per uint32, same idx)
    //   [32,48M):  Khi bf16 [bh][t][d]    [48,64M): Klo
    //   [64,80M):  Vthi bf16 [bh][d][t]   [80,96M): Vtlo
    //   [96,102M): Wqkv hi   [102,108M): Wqkv lo
    //   [108,110M): Wout hi  [110,112M): Wout lo
    //   [112M,+512K): rope table
    // d_out (32 MB) holds Xhi/Xlo until gemm_out overwrites it.
    char* wsb = (char*)d_ws;
    float*          Qf   = (float*)(wsb);
    unsigned int*   Opk  = (unsigned int*)(wsb);
    unsigned short* Khig = (unsigned short*)(wsb + (size_t)32 * 1048576);
    unsigned short* Klog = (unsigned short*)(wsb + (size_t)48 * 1048576);
    unsigned short* Vthig= (unsigned short*)(wsb + (size_t)64 * 1048576);
    unsigned short* Vtlog= (unsigned short*)(wsb + (size_t)80 * 1048576);
    short*          Whi  = (short*)(wsb + (size_t)96  * 1048576);
    short*          Wlo  = (short*)(wsb + (size_t)102 * 1048576);
    short*          WOhi = (short*)(wsb + (size_t)108 * 1048576);
    short*          WOlo = (short*)(wsb + (size_t)110 * 1048576);
    float*          tab  = (float*)(wsb + (size_t)112 * 1048576);

    short* Xhi = (short*)d_out;
    short* Xlo = (short*)d_out + 8388608;

    rope_table<<<256, 256, 0, stream>>>(tab);
    cast_split<<<8192, 256, 0, stream>>>(x,    Xhi,  Xlo,  2097152);
    cast_split<<<3072, 256, 0, stream>>>(wqkv, Whi,  Wlo,  786432);
    cast_split<<<1024, 256, 0, stream>>>(wout, WOhi, WOlo, 262144);

    dim3 g1(24, 64);
    gemm_qkv_mfma<<<g1, 256, 0, stream>>>(Xhi, Xlo, Whi, Wlo, tab, Qf,
                                          Khig, Klog, Vthig, Vtlog);

    dim3 g2(16, 64);
    attn_fwd_mfma<<<g2, 256, 0, stream>>>(Qf, Khig, Klog, Vthig, Vtlog, Opk);

    dim3 g3(8, 64);
    gemm_out_mfma<<<g3, 256, 0, stream>>>(Opk, WOhi, WOlo, out);
}